// Round 1
// baseline (572.763 us; speedup 1.0000x reference)
//
#include <hip/hip_runtime.h>
#include <cstdint>

// ---------------------------------------------------------------------------
// R-FCN head on MI355X.
//   x = relu(w_conv1 @ base_feat)            -> bf16 MFMA GEMM, channel-last
//   S = 2D integral image of x (fp32)        -> two scan kernels
//   score[roi,c] = sum_ij w[c,ij] . u[roi,ij]  (u = region sum / area)
//                                            -> bf16 MFMA GEMM over ij chunks
//   outputs: softmax(cls_score/49), bbox/49
// ---------------------------------------------------------------------------

typedef __attribute__((ext_vector_type(8))) short short8;   // 8 bf16 (4 VGPRs)
typedef __attribute__((ext_vector_type(4))) short short4v;
typedef __attribute__((ext_vector_type(4))) float f32x4;

// workspace layout (bytes)
#define OFF_FEATT 0ull          // bf16 [4][4096][2048] = 67108864 ; later S1 f32 [4][64][64][1024]
#define OFF_W1    67108864ull   // bf16 [1024][2048]    = 4194304
#define OFF_WC    71303168ull   // bf16 [128][49][1024] = 12845056 (rows 105..127 zero)
#define OFF_DESC  84148224ull   // int  [1280][49][8]   = 2007040
#define OFF_SCORE 86155264ull   // f32  [1280][128]     = 655360
#define OFF_X     86810624ull   // f32  [4][4096][1024] = 67108864 (X, then Sfinal)
// total 153,919,488 bytes

__device__ __forceinline__ unsigned short f2bf(float f) {
  unsigned u = __float_as_uint(f);
  u += 0x7fffu + ((u >> 16) & 1u);        // round-to-nearest-even
  return (unsigned short)(u >> 16);
}

__device__ __forceinline__ void gload16(const void* g, void* l) {
  __builtin_amdgcn_global_load_lds((const __attribute__((address_space(1))) void*)g,
                                   (__attribute__((address_space(3))) void*)l, 16, 0, 0);
}

// --- weight conversions ----------------------------------------------------
__global__ __launch_bounds__(256) void k_cvt_w1(const float* __restrict__ src,
                                                unsigned short* __restrict__ dst) {
  int t = blockIdx.x * 256 + threadIdx.x;
  long e = (long)t * 4;
  if (e >= 1024 * 2048) return;
  float4 q = *(const float4*)(src + e);
  short4v s = {(short)f2bf(q.x), (short)f2bf(q.y), (short)f2bf(q.z), (short)f2bf(q.w)};
  *(short4v*)(dst + e) = s;
}

// Wc[c][ij][k]: c<21 -> w_cls[c*49+ij], c<105 -> w_bbox[(c-21)*49+ij], else 0
__global__ __launch_bounds__(256) void k_cvt_wcomb(const float* __restrict__ wcls,
                                                   const float* __restrict__ wbbox,
                                                   unsigned short* __restrict__ dst) {
  int t = blockIdx.x * 256 + threadIdx.x;
  if (t >= 128 * 49 * 256) return;
  size_t e = (size_t)t * 4;
  int c = (int)(e / 50176);
  int rem = (int)(e - (size_t)c * 50176);
  int ij = rem >> 10, k = rem & 1023;
  float4 q = make_float4(0.f, 0.f, 0.f, 0.f);
  if (c < 21)       q = *(const float4*)(wcls + (size_t)(c * 49 + ij) * 1024 + k);
  else if (c < 105) q = *(const float4*)(wbbox + (size_t)((c - 21) * 49 + ij) * 1024 + k);
  short4v s = {(short)f2bf(q.x), (short)f2bf(q.y), (short)f2bf(q.z), (short)f2bf(q.w)};
  *(short4v*)(dst + e) = s;
}

// --- base_feat [b][c][s] fp32 -> featT [b][s][c] bf16 ----------------------
__global__ __launch_bounds__(256) void k_tpose(const float* __restrict__ src,
                                               unsigned short* __restrict__ dst) {
  __shared__ float tile[64][65];
  int s0 = blockIdx.x * 64, c0 = blockIdx.y * 64, b = blockIdx.z;
  int tx = threadIdx.x & 63, ty = threadIdx.x >> 6;
  const float* sp = src + ((size_t)b * 2048 + c0) * 4096 + s0;
#pragma unroll
  for (int i = 0; i < 16; i++) {
    int cl = ty * 16 + i;
    tile[cl][tx] = sp[(size_t)cl * 4096 + tx];
  }
  __syncthreads();
  unsigned short* dp = dst + ((size_t)b * 4096 + s0) * 2048 + c0;
#pragma unroll
  for (int i = 0; i < 16; i++) {
    int sl = ty * 16 + i;
    dp[(size_t)sl * 2048 + tx] = f2bf(tile[tx][sl]);
  }
}

// --- conv1: X[b][s][o] = relu(sum_k featT[b][s][k] * w1[o][k]) -------------
__global__ __launch_bounds__(256) void k_gemm_conv1(const short* __restrict__ A,
                                                    const short* __restrict__ Bw,
                                                    float* __restrict__ X) {
  int mt = blockIdx.x, nt = blockIdx.y, b = blockIdx.z;
  __shared__ short As[128 * 64];   // [m][k] rows k-contiguous
  __shared__ short Bs[128 * 64];   // [n][k]
  int tid = threadIdx.x, lane = tid & 63, wave = tid >> 6;
  int wm = wave >> 1, wn = wave & 1;
  f32x4 acc[4][4];
#pragma unroll
  for (int i = 0; i < 4; i++)
#pragma unroll
    for (int j = 0; j < 4; j++) acc[i][j] = (f32x4){0.f, 0.f, 0.f, 0.f};

  const short* Ab = A + ((size_t)b * 4096 + (size_t)mt * 128) * 2048;
  const short* Bb = Bw + (size_t)nt * 128 * 2048;
  int lr = lane >> 3;          // row within 8-row chunk
  int lc = (lane & 7) * 8;     // k element

  for (int k0 = 0; k0 < 2048; k0 += 64) {
#pragma unroll
    for (int i = 0; i < 4; i++) {
      int row = i * 32 + wave * 8 + lr;
      gload16(Ab + (size_t)row * 2048 + k0 + lc, (char*)As + (i * 32 + wave * 8) * 128);
      gload16(Bb + (size_t)row * 2048 + k0 + lc, (char*)Bs + (i * 32 + wave * 8) * 128);
    }
    __syncthreads();
#pragma unroll
    for (int kt = 0; kt < 2; kt++) {
      int ko = kt * 32 + (lane >> 4) * 8;
      short8 af[4], bfr[4];
#pragma unroll
      for (int i = 0; i < 4; i++)
        af[i] = *(const short8*)(As + (wm * 64 + i * 16 + (lane & 15)) * 64 + ko);
#pragma unroll
      for (int j = 0; j < 4; j++)
        bfr[j] = *(const short8*)(Bs + (wn * 64 + j * 16 + (lane & 15)) * 64 + ko);
#pragma unroll
      for (int i = 0; i < 4; i++)
#pragma unroll
        for (int j = 0; j < 4; j++)
          acc[i][j] = __builtin_amdgcn_mfma_f32_16x16x32_bf16(af[i], bfr[j], acc[i][j], 0, 0, 0);
    }
    __syncthreads();
  }
  float* Xb = X + ((size_t)b * 4096 + (size_t)mt * 128) * 1024 + nt * 128;
#pragma unroll
  for (int i = 0; i < 4; i++)
#pragma unroll
    for (int j = 0; j < 4; j++) {
      int row = wm * 64 + i * 16 + (lane >> 4) * 4;
      int col = wn * 64 + j * 16 + (lane & 15);
#pragma unroll
      for (int r = 0; r < 4; r++)
        Xb[(size_t)(row + r) * 1024 + col] = fmaxf(acc[i][j][r], 0.f);
    }
}

// --- integral image: horizontal then vertical inclusive scans --------------
__global__ __launch_bounds__(256) void k_hscan(const float* __restrict__ X,
                                               float* __restrict__ S1) {
  int t = blockIdx.x * 256 + threadIdx.x;   // [0, 4*64*1024)
  int c = t & 1023;
  int bh = t >> 10;                          // b*64 + h
  size_t base = (size_t)bh * 64 * 1024 + c;
  float acc = 0.f;
  for (int w = 0; w < 64; w++) {
    size_t idx = base + (size_t)w * 1024;
    acc += X[idx];
    S1[idx] = acc;
  }
}
__global__ __launch_bounds__(256) void k_vscan(const float* __restrict__ S1,
                                               float* __restrict__ Sf) {
  int t = blockIdx.x * 256 + threadIdx.x;
  int c = t & 1023;
  int bw = t >> 10;
  int b = bw >> 6, w = bw & 63;
  size_t base = ((size_t)b * 4096 + w) * 1024 + c;
  float acc = 0.f;
  for (int h = 0; h < 64; h++) {
    size_t idx = base + (size_t)h * 64 * 1024;
    acc += S1[idx];
    Sf[idx] = acc;
  }
}

// --- per-(roi,bin) descriptors: 4 corner offsets + 1/area ------------------
// fp32 ops mirror the reference exactly (unfused mul/add, floor/ceil, clip)
__global__ __launch_bounds__(256) void k_desc(const float* __restrict__ rois,
                                              int* __restrict__ desc) {
  int t = blockIdx.x * 256 + threadIdx.x;
  if (t >= 1280 * 49) return;
  int roi = t / 49, ij = t - roi * 49;
  int* d = desc + (size_t)t * 8;
  if (roi >= 1200) { d[0] = d[1] = d[2] = d[3] = -1; d[4] = 0; return; }
  const float* r = rois + (size_t)roi * 5;
  int b = (int)r[0];
  float x1 = __fmul_rn(floorf(__fadd_rn(r[1], 0.5f)), 0.0625f);
  float y1 = __fmul_rn(floorf(__fadd_rn(r[2], 0.5f)), 0.0625f);
  float x2 = __fmul_rn(floorf(__fadd_rn(__fadd_rn(r[3], 1.0f), 0.5f)), 0.0625f);
  float y2 = __fmul_rn(floorf(__fadd_rn(__fadd_rn(r[4], 1.0f), 0.5f)), 0.0625f);
  float bw = __fdiv_rn(fmaxf(__fsub_rn(x2, x1), 0.1f), 7.0f);
  float bh = __fdiv_rn(fmaxf(__fsub_rn(y2, y1), 0.1f), 7.0f);
  int i = ij / 7, j = ij - (ij / 7) * 7;
  float fi = (float)i, fj = (float)j;
  int hs = (int)fminf(fmaxf(floorf(__fadd_rn(__fmul_rn(fi, bh), y1)), 0.f), 64.f);
  int he = (int)fminf(fmaxf(ceilf(__fadd_rn(__fmul_rn(__fadd_rn(fi, 1.f), bh), y1)), 0.f), 64.f);
  int wsx = (int)fminf(fmaxf(floorf(__fadd_rn(__fmul_rn(fj, bw), x1)), 0.f), 64.f);
  int we = (int)fminf(fmaxf(ceilf(__fadd_rn(__fmul_rn(__fadd_rn(fj, 1.f), bw), x1)), 0.f), 64.f);
  int dh = max(he - hs, 0), dw = max(we - wsx, 0);
  float inv = (dh * dw > 0) ? 1.0f / (float)(dh * dw) : 0.f;
  auto off = [&](int h, int w) -> int {
    return (h > 0 && w > 0) ? (((b * 64 + (h - 1)) * 64 + (w - 1)) * 1024) : -1;
  };
  d[0] = off(he, we);   // +
  d[1] = off(hs, we);   // -
  d[2] = off(he, wsx);  // -
  d[3] = off(hs, wsx);  // +
  ((float*)d)[4] = inv;
}

// --- pool-GEMM: score[roi][c] += sum_k u[roi][ij][k] * Wc[c][ij][k] --------
__global__ __launch_bounds__(256) void k_poolgemm(const float* __restrict__ Sf,
                                                  const int* __restrict__ desc,
                                                  const unsigned short* __restrict__ Wc,
                                                  float* __restrict__ score) {
  int mt = blockIdx.x;   // 0..9 roi tile
  int ij = blockIdx.y;   // 0..48 bin = K chunk
  __shared__ unsigned short As[128 * 72];  // u bf16, padded rows (72) to break bank conflicts
  __shared__ unsigned short Bs[128 * 64];
  __shared__ int doff[128][4];
  __shared__ float dinv[128];
  int tid = threadIdx.x, lane = tid & 63, wave = tid >> 6;
  if (tid < 128) {
    const int* d = desc + ((size_t)(mt * 128 + tid) * 49 + ij) * 8;
    doff[tid][0] = d[0]; doff[tid][1] = d[1]; doff[tid][2] = d[2]; doff[tid][3] = d[3];
    dinv[tid] = ((const float*)d)[4];
  }
  __syncthreads();
  int wm = wave >> 1, wn = wave & 1;
  f32x4 acc[4][4];
#pragma unroll
  for (int i = 0; i < 4; i++)
#pragma unroll
    for (int j = 0; j < 4; j++) acc[i][j] = (f32x4){0.f, 0.f, 0.f, 0.f};

  int ar = tid >> 4;          // 0..15
  int ak = (tid & 15) * 4;    // 0..60

  for (int k0 = 0; k0 < 1024; k0 += 64) {
    // build A tile: u values, bf16
#pragma unroll
    for (int it = 0; it < 8; it++) {
      int rr = it * 16 + ar;
      int o0 = doff[rr][0], o1 = doff[rr][1], o2 = doff[rr][2], o3 = doff[rr][3];
      float inv = dinv[rr];
      int k = k0 + ak;
      float ax = 0.f, ay = 0.f, az = 0.f, aw = 0.f;
      if (o0 >= 0) { float4 q = *(const float4*)(Sf + o0 + k); ax += q.x; ay += q.y; az += q.z; aw += q.w; }
      if (o1 >= 0) { float4 q = *(const float4*)(Sf + o1 + k); ax -= q.x; ay -= q.y; az -= q.z; aw -= q.w; }
      if (o2 >= 0) { float4 q = *(const float4*)(Sf + o2 + k); ax -= q.x; ay -= q.y; az -= q.z; aw -= q.w; }
      if (o3 >= 0) { float4 q = *(const float4*)(Sf + o3 + k); ax += q.x; ay += q.y; az += q.z; aw += q.w; }
      short4v s = {(short)f2bf(ax * inv), (short)f2bf(ay * inv),
                   (short)f2bf(az * inv), (short)f2bf(aw * inv)};
      *(short4v*)&As[rr * 72 + ak] = s;
    }
    // stage B tile (weights) via async global->LDS
#pragma unroll
    for (int i2 = 0; i2 < 4; i2++) {
      int row = i2 * 32 + wave * 8 + (lane >> 3);
      gload16(Wc + ((size_t)row * 49 + ij) * 1024 + (size_t)k0 + (lane & 7) * 8,
              (char*)Bs + (i2 * 32 + wave * 8) * 128);
    }
    __syncthreads();
#pragma unroll
    for (int kt = 0; kt < 2; kt++) {
      int ko = kt * 32 + (lane >> 4) * 8;
      short8 af[4], bfr[4];
#pragma unroll
      for (int i = 0; i < 4; i++)
        af[i] = *(const short8*)((const short*)As + (wm * 64 + i * 16 + (lane & 15)) * 72 + ko);
#pragma unroll
      for (int j = 0; j < 4; j++)
        bfr[j] = *(const short8*)((const short*)Bs + (wn * 64 + j * 16 + (lane & 15)) * 64 + ko);
#pragma unroll
      for (int i = 0; i < 4; i++)
#pragma unroll
        for (int j = 0; j < 4; j++)
          acc[i][j] = __builtin_amdgcn_mfma_f32_16x16x32_bf16(af[i], bfr[j], acc[i][j], 0, 0, 0);
    }
    __syncthreads();
  }
  int roi0 = mt * 128 + wm * 64, c0 = wn * 64;
#pragma unroll
  for (int i = 0; i < 4; i++)
#pragma unroll
    for (int j = 0; j < 4; j++) {
      int rr = roi0 + i * 16 + (lane >> 4) * 4;
      int cc = c0 + j * 16 + (lane & 15);
#pragma unroll
      for (int r = 0; r < 4; r++)
        atomicAdd(&score[(size_t)(rr + r) * 128 + cc], acc[i][j][r]);
    }
}

// --- epilogue: softmax(cls/49) + bbox/49 -----------------------------------
__global__ __launch_bounds__(256) void k_final(const float* __restrict__ score,
                                               float* __restrict__ out) {
  int t = blockIdx.x * 256 + threadIdx.x;
  if (t < 1200) {
    float s[21];
    float mx = -1e30f;
#pragma unroll
    for (int c = 0; c < 21; c++) {
      s[c] = score[(size_t)t * 128 + c] * (1.f / 49.f);
      mx = fmaxf(mx, s[c]);
    }
    float sum = 0.f;
#pragma unroll
    for (int c = 0; c < 21; c++) { s[c] = expf(s[c] - mx); sum += s[c]; }
    float rs = 1.f / sum;
#pragma unroll
    for (int c = 0; c < 21; c++) out[(size_t)t * 21 + c] = s[c] * rs;
  }
  if (t < 100800) {
    int roi = t / 84, c = t - (t / 84) * 84;
    out[25200 + t] = score[(size_t)roi * 128 + 21 + c] * (1.f / 49.f);
  }
}

extern "C" void kernel_launch(void* const* d_in, const int* in_sizes, int n_in,
                              void* d_out, int out_size, void* d_ws, size_t ws_size,
                              hipStream_t stream) {
  const float* base_feat = (const float*)d_in[0];
  const float* rois      = (const float*)d_in[1];
  const float* w_conv1   = (const float*)d_in[2];
  const float* w_cls     = (const float*)d_in[3];
  const float* w_bbox    = (const float*)d_in[4];
  float* out = (float*)d_out;
  char* ws = (char*)d_ws;

  unsigned short* featT = (unsigned short*)(ws + OFF_FEATT);
  unsigned short* w1b   = (unsigned short*)(ws + OFF_W1);
  unsigned short* Wc    = (unsigned short*)(ws + OFF_WC);
  int*            desc  = (int*)(ws + OFF_DESC);
  float*          score = (float*)(ws + OFF_SCORE);
  float*          X     = (float*)(ws + OFF_X);
  float*          S1    = (float*)(ws + OFF_FEATT);  // aliases featT (dead after GEMM)
  float*          Sf    = X;                          // vscan overwrites X in a disjoint pass

  k_cvt_w1<<<2048, 256, 0, stream>>>(w_conv1, w1b);
  k_cvt_wcomb<<<6272, 256, 0, stream>>>(w_cls, w_bbox, Wc);
  k_tpose<<<dim3(64, 32, 4), 256, 0, stream>>>(base_feat, featT);
  k_gemm_conv1<<<dim3(32, 8, 4), 256, 0, stream>>>((const short*)featT, (const short*)w1b, X);
  k_hscan<<<1024, 256, 0, stream>>>(X, S1);
  k_vscan<<<1024, 256, 0, stream>>>(S1, Sf);
  k_desc<<<245, 256, 0, stream>>>(rois, desc);
  hipMemsetAsync(score, 0, (size_t)1280 * 128 * sizeof(float), stream);
  k_poolgemm<<<dim3(10, 49), 256, 0, stream>>>(Sf, desc, Wc, score);
  k_final<<<394, 256, 0, stream>>>(score, out);
}

// Round 2
// 538.069 us; speedup vs baseline: 1.0645x; 1.0645x over previous
//
#include <hip/hip_runtime.h>
#include <cstdint>

// ---------------------------------------------------------------------------
// R-FCN head on MI355X.  Round 2: split pool-GEMM into
//   k_ubuild   : streaming gather  U[roi][ij][k] bf16  (latency-tolerant)
//   k_poolgemm2: pure bf16 MFMA GEMM (A staged via global_load_lds)
//   k_reduce   : sum 49 ij-partials (replaces 8M atomics)
// Rois processed in 2 halves of 640 so U (64.2MB) + P (7.0MB) fit the dead
// featT+w1 region [0, 71.3MB).
// ---------------------------------------------------------------------------

typedef __attribute__((ext_vector_type(8))) short short8;   // 8 bf16 (4 VGPRs)
typedef __attribute__((ext_vector_type(4))) short short4v;
typedef __attribute__((ext_vector_type(4))) float f32x4;

// workspace layout (bytes)
#define OFF_FEATT 0ull          // bf16 [4][4096][2048] = 67108864 ; later S1 f32; later U+P
#define OFF_W1    67108864ull   // bf16 [1024][2048]    = 4194304  (dead after conv1)
#define OFF_U     0ull          // bf16 [640][49][1024] = 64225280
#define OFF_P     64225280ull   // bf16 [49][640][112]  = 7024640  (ends 71249920 <= 71303168)
#define OFF_WC    71303168ull   // bf16 [128][49][1024] = 12845056 (rows 105..127 zero)
#define OFF_DESC  84148224ull   // int  [1280][49][8]   = 2007040
#define OFF_SCORE 86155264ull   // f32  [1280][128]     = 655360
#define OFF_X     86810624ull   // f32  [4][4096][1024] = 67108864 (X, then Sf)
// total 153,919,488 bytes

__device__ __forceinline__ unsigned short f2bf(float f) {
  unsigned u = __float_as_uint(f);
  u += 0x7fffu + ((u >> 16) & 1u);        // round-to-nearest-even
  return (unsigned short)(u >> 16);
}
__device__ __forceinline__ float bf2f(unsigned short h) {
  return __uint_as_float(((unsigned)h) << 16);
}

__device__ __forceinline__ void gload16(const void* g, void* l) {
  __builtin_amdgcn_global_load_lds((const __attribute__((address_space(1))) void*)g,
                                   (__attribute__((address_space(3))) void*)l, 16, 0, 0);
}

// --- weight conversions ----------------------------------------------------
__global__ __launch_bounds__(256) void k_cvt_w1(const float* __restrict__ src,
                                                unsigned short* __restrict__ dst) {
  int t = blockIdx.x * 256 + threadIdx.x;
  long e = (long)t * 4;
  if (e >= 1024 * 2048) return;
  float4 q = *(const float4*)(src + e);
  short4v s = {(short)f2bf(q.x), (short)f2bf(q.y), (short)f2bf(q.z), (short)f2bf(q.w)};
  *(short4v*)(dst + e) = s;
}

// Wc[c][ij][k]: c<21 -> w_cls[c*49+ij], c<105 -> w_bbox[(c-21)*49+ij], else 0
__global__ __launch_bounds__(256) void k_cvt_wcomb(const float* __restrict__ wcls,
                                                   const float* __restrict__ wbbox,
                                                   unsigned short* __restrict__ dst) {
  int t = blockIdx.x * 256 + threadIdx.x;
  if (t >= 128 * 49 * 256) return;
  size_t e = (size_t)t * 4;
  int c = (int)(e / 50176);
  int rem = (int)(e - (size_t)c * 50176);
  int ij = rem >> 10, k = rem & 1023;
  float4 q = make_float4(0.f, 0.f, 0.f, 0.f);
  if (c < 21)       q = *(const float4*)(wcls + (size_t)(c * 49 + ij) * 1024 + k);
  else if (c < 105) q = *(const float4*)(wbbox + (size_t)((c - 21) * 49 + ij) * 1024 + k);
  short4v s = {(short)f2bf(q.x), (short)f2bf(q.y), (short)f2bf(q.z), (short)f2bf(q.w)};
  *(short4v*)(dst + e) = s;
}

// --- base_feat [b][c][s] fp32 -> featT [b][s][c] bf16 ----------------------
__global__ __launch_bounds__(256) void k_tpose(const float* __restrict__ src,
                                               unsigned short* __restrict__ dst) {
  __shared__ float tile[64][65];
  int s0 = blockIdx.x * 64, c0 = blockIdx.y * 64, b = blockIdx.z;
  int tx = threadIdx.x & 63, ty = threadIdx.x >> 6;
  const float* sp = src + ((size_t)b * 2048 + c0) * 4096 + s0;
#pragma unroll
  for (int i = 0; i < 16; i++) {
    int cl = ty * 16 + i;
    tile[cl][tx] = sp[(size_t)cl * 4096 + tx];
  }
  __syncthreads();
  unsigned short* dp = dst + ((size_t)b * 4096 + s0) * 2048 + c0;
#pragma unroll
  for (int i = 0; i < 16; i++) {
    int sl = ty * 16 + i;
    dp[(size_t)sl * 2048 + tx] = f2bf(tile[tx][sl]);
  }
}

// --- conv1: X[b][s][o] = relu(sum_k featT[b][s][k] * w1[o][k]) -------------
__global__ __launch_bounds__(256) void k_gemm_conv1(const short* __restrict__ A,
                                                    const short* __restrict__ Bw,
                                                    float* __restrict__ X) {
  int mt = blockIdx.x, nt = blockIdx.y, b = blockIdx.z;
  __shared__ short As[128 * 64];   // [m][k] rows k-contiguous
  __shared__ short Bs[128 * 64];   // [n][k]
  int tid = threadIdx.x, lane = tid & 63, wave = tid >> 6;
  int wm = wave >> 1, wn = wave & 1;
  f32x4 acc[4][4];
#pragma unroll
  for (int i = 0; i < 4; i++)
#pragma unroll
    for (int j = 0; j < 4; j++) acc[i][j] = (f32x4){0.f, 0.f, 0.f, 0.f};

  const short* Ab = A + ((size_t)b * 4096 + (size_t)mt * 128) * 2048;
  const short* Bb = Bw + (size_t)nt * 128 * 2048;
  int lr = lane >> 3;          // row within 8-row chunk
  int lc = (lane & 7) * 8;     // k element

  for (int k0 = 0; k0 < 2048; k0 += 64) {
#pragma unroll
    for (int i = 0; i < 4; i++) {
      int row = i * 32 + wave * 8 + lr;
      gload16(Ab + (size_t)row * 2048 + k0 + lc, (char*)As + (i * 32 + wave * 8) * 128);
      gload16(Bb + (size_t)row * 2048 + k0 + lc, (char*)Bs + (i * 32 + wave * 8) * 128);
    }
    __syncthreads();
#pragma unroll
    for (int kt = 0; kt < 2; kt++) {
      int ko = kt * 32 + (lane >> 4) * 8;
      short8 af[4], bfr[4];
#pragma unroll
      for (int i = 0; i < 4; i++)
        af[i] = *(const short8*)(As + (wm * 64 + i * 16 + (lane & 15)) * 64 + ko);
#pragma unroll
      for (int j = 0; j < 4; j++)
        bfr[j] = *(const short8*)(Bs + (wn * 64 + j * 16 + (lane & 15)) * 64 + ko);
#pragma unroll
      for (int i = 0; i < 4; i++)
#pragma unroll
        for (int j = 0; j < 4; j++)
          acc[i][j] = __builtin_amdgcn_mfma_f32_16x16x32_bf16(af[i], bfr[j], acc[i][j], 0, 0, 0);
    }
    __syncthreads();
  }
  float* Xb = X + ((size_t)b * 4096 + (size_t)mt * 128) * 1024 + nt * 128;
#pragma unroll
  for (int i = 0; i < 4; i++)
#pragma unroll
    for (int j = 0; j < 4; j++) {
      int row = wm * 64 + i * 16 + (lane >> 4) * 4;
      int col = wn * 64 + j * 16 + (lane & 15);
#pragma unroll
      for (int r = 0; r < 4; r++)
        Xb[(size_t)(row + r) * 1024 + col] = fmaxf(acc[i][j][r], 0.f);
    }
}

// --- integral image: horizontal then vertical inclusive scans --------------
__global__ __launch_bounds__(256) void k_hscan(const float* __restrict__ X,
                                               float* __restrict__ S1) {
  int t = blockIdx.x * 256 + threadIdx.x;   // [0, 4*64*1024)
  int c = t & 1023;
  int bh = t >> 10;                          // b*64 + h
  size_t base = (size_t)bh * 64 * 1024 + c;
  float acc = 0.f;
  for (int w = 0; w < 64; w++) {
    size_t idx = base + (size_t)w * 1024;
    acc += X[idx];
    S1[idx] = acc;
  }
}
__global__ __launch_bounds__(256) void k_vscan(const float* __restrict__ S1,
                                               float* __restrict__ Sf) {
  int t = blockIdx.x * 256 + threadIdx.x;
  int c = t & 1023;
  int bw = t >> 10;
  int b = bw >> 6, w = bw & 63;
  size_t base = ((size_t)b * 4096 + w) * 1024 + c;
  float acc = 0.f;
  for (int h = 0; h < 64; h++) {
    size_t idx = base + (size_t)h * 64 * 1024;
    acc += S1[idx];
    Sf[idx] = acc;
  }
}

// --- per-(roi,bin) descriptors: 4 corner offsets + 1/area ------------------
__global__ __launch_bounds__(256) void k_desc(const float* __restrict__ rois,
                                              int* __restrict__ desc) {
  int t = blockIdx.x * 256 + threadIdx.x;
  if (t >= 1280 * 49) return;
  int roi = t / 49, ij = t - roi * 49;
  int* d = desc + (size_t)t * 8;
  if (roi >= 1200) { d[0] = d[1] = d[2] = d[3] = -1; d[4] = 0; return; }
  const float* r = rois + (size_t)roi * 5;
  int b = (int)r[0];
  float x1 = __fmul_rn(floorf(__fadd_rn(r[1], 0.5f)), 0.0625f);
  float y1 = __fmul_rn(floorf(__fadd_rn(r[2], 0.5f)), 0.0625f);
  float x2 = __fmul_rn(floorf(__fadd_rn(__fadd_rn(r[3], 1.0f), 0.5f)), 0.0625f);
  float y2 = __fmul_rn(floorf(__fadd_rn(__fadd_rn(r[4], 1.0f), 0.5f)), 0.0625f);
  float bw = __fdiv_rn(fmaxf(__fsub_rn(x2, x1), 0.1f), 7.0f);
  float bh = __fdiv_rn(fmaxf(__fsub_rn(y2, y1), 0.1f), 7.0f);
  int i = ij / 7, j = ij - (ij / 7) * 7;
  float fi = (float)i, fj = (float)j;
  int hs = (int)fminf(fmaxf(floorf(__fadd_rn(__fmul_rn(fi, bh), y1)), 0.f), 64.f);
  int he = (int)fminf(fmaxf(ceilf(__fadd_rn(__fmul_rn(__fadd_rn(fi, 1.f), bh), y1)), 0.f), 64.f);
  int wsx = (int)fminf(fmaxf(floorf(__fadd_rn(__fmul_rn(fj, bw), x1)), 0.f), 64.f);
  int we = (int)fminf(fmaxf(ceilf(__fadd_rn(__fmul_rn(__fadd_rn(fj, 1.f), bw), x1)), 0.f), 64.f);
  int dh = max(he - hs, 0), dw = max(we - wsx, 0);
  float inv = (dh * dw > 0) ? 1.0f / (float)(dh * dw) : 0.f;
  auto off = [&](int h, int w) -> int {
    return (h > 0 && w > 0) ? (((b * 64 + (h - 1)) * 64 + (w - 1)) * 1024) : -1;
  };
  d[0] = off(he, we);   // +
  d[1] = off(hs, we);   // -
  d[2] = off(he, wsx);  // -
  d[3] = off(hs, wsx);  // +
  ((float*)d)[4] = inv;
}

// --- u-build: U[roi_local][ij][k] bf16 = (corner diffs)*inv ----------------
// One block per (roi_local, ij); 256 threads x 4 k-floats. Pure streaming,
// no barriers, block-uniform branches; latency hidden by occupancy.
__global__ __launch_bounds__(256) void k_ubuild(const float* __restrict__ Sf,
                                                const int* __restrict__ desc,
                                                unsigned short* __restrict__ U) {
  int t = blockIdx.x;                 // roi_local*49 + ij
  const int* d = desc + (size_t)t * 8;
  int o0 = d[0], o1 = d[1], o2 = d[2], o3 = d[3];
  float inv = ((const float*)d)[4];
  int k = threadIdx.x * 4;
  float ax = 0.f, ay = 0.f, az = 0.f, aw = 0.f;
  if (o0 >= 0) { float4 q = *(const float4*)(Sf + o0 + k); ax += q.x; ay += q.y; az += q.z; aw += q.w; }
  if (o1 >= 0) { float4 q = *(const float4*)(Sf + o1 + k); ax -= q.x; ay -= q.y; az -= q.z; aw -= q.w; }
  if (o2 >= 0) { float4 q = *(const float4*)(Sf + o2 + k); ax -= q.x; ay -= q.y; az -= q.z; aw -= q.w; }
  if (o3 >= 0) { float4 q = *(const float4*)(Sf + o3 + k); ax += q.x; ay += q.y; az += q.z; aw += q.w; }
  short4v s = {(short)f2bf(ax * inv), (short)f2bf(ay * inv),
               (short)f2bf(az * inv), (short)f2bf(aw * inv)};
  *(short4v*)(U + (size_t)t * 1024 + k) = s;
}

// --- pool-GEMM (per 640-roi half): P[ij][roi][c] = sum_k U*Wc --------------
// 64-roi x 128-c tile, K=1024 per block, grid (10, 49) = 490 blocks.
__global__ __launch_bounds__(256) void k_poolgemm2(const unsigned short* __restrict__ U,
                                                   const unsigned short* __restrict__ Wc,
                                                   unsigned short* __restrict__ P) {
  int mt = blockIdx.x;   // 0..9 (64-roi tile)
  int ij = blockIdx.y;   // 0..48
  __shared__ short As[64 * 64];    // [roi][k] bf16
  __shared__ short Bs[128 * 64];   // [c][k]
  int tid = threadIdx.x, lane = tid & 63, wave = tid >> 6;
  f32x4 acc[4][2];
#pragma unroll
  for (int i = 0; i < 4; i++)
#pragma unroll
    for (int j = 0; j < 2; j++) acc[i][j] = (f32x4){0.f, 0.f, 0.f, 0.f};

  const unsigned short* Ab = U + ((size_t)mt * 64 * 49 + ij) * 1024;
  const unsigned short* Bb = Wc + (size_t)ij * 1024;
  int lr = lane >> 3, lc = (lane & 7) * 8;

  for (int k0 = 0; k0 < 1024; k0 += 64) {
    {  // A: 64 rows, 2 wave-loads per wave
#pragma unroll
      for (int i = 0; i < 2; i++) {
        int row = i * 32 + wave * 8 + lr;
        gload16(Ab + (size_t)row * (49 * 1024) + k0 + lc, (char*)As + (i * 32 + wave * 8) * 128);
      }
    }
    {  // B: 128 rows, 4 wave-loads per wave
#pragma unroll
      for (int i = 0; i < 4; i++) {
        int row = i * 32 + wave * 8 + lr;
        gload16(Bb + (size_t)row * (49 * 1024) + k0 + lc, (char*)Bs + (i * 32 + wave * 8) * 128);
      }
    }
    __syncthreads();
#pragma unroll
    for (int kt = 0; kt < 2; kt++) {
      int ko = kt * 32 + (lane >> 4) * 8;
      short8 af[4], bfr[2];
#pragma unroll
      for (int i = 0; i < 4; i++)
        af[i] = *(const short8*)(As + (i * 16 + (lane & 15)) * 64 + ko);
#pragma unroll
      for (int j = 0; j < 2; j++)
        bfr[j] = *(const short8*)(Bs + (wave * 32 + j * 16 + (lane & 15)) * 64 + ko);
#pragma unroll
      for (int i = 0; i < 4; i++)
#pragma unroll
        for (int j = 0; j < 2; j++)
          acc[i][j] = __builtin_amdgcn_mfma_f32_16x16x32_bf16(af[i], bfr[j], acc[i][j], 0, 0, 0);
    }
    __syncthreads();
  }
  // store partials P[ij][640][112] bf16 (c>=112 dropped; only c<105 used)
  unsigned short* Pb = P + (size_t)ij * 640 * 112;
#pragma unroll
  for (int i = 0; i < 4; i++)
#pragma unroll
    for (int j = 0; j < 2; j++) {
      int cc = wave * 32 + j * 16 + (lane & 15);
      if (cc < 112) {
        int rbase = mt * 64 + i * 16 + (lane >> 4) * 4;
#pragma unroll
        for (int r = 0; r < 4; r++)
          Pb[(size_t)(rbase + r) * 112 + cc] = f2bf(acc[i][j][r]);
      }
    }
}

// --- reduce 49 ij-partials -> score (per half) -----------------------------
__global__ __launch_bounds__(256) void k_reduce(const unsigned short* __restrict__ P,
                                                float* __restrict__ score) {
  int t = blockIdx.x * 256 + threadIdx.x;   // 640*112
  if (t >= 640 * 112) return;
  int roi = t / 112, c = t - roi * 112;
  float s = 0.f;
#pragma unroll 7
  for (int ij = 0; ij < 49; ij++) s += bf2f(P[(size_t)ij * 640 * 112 + t]);
  score[(size_t)roi * 128 + c] = s;
}

// --- epilogue: softmax(cls/49) + bbox/49 -----------------------------------
__global__ __launch_bounds__(256) void k_final(const float* __restrict__ score,
                                               float* __restrict__ out) {
  int t = blockIdx.x * 256 + threadIdx.x;
  if (t < 1200) {
    float s[21];
    float mx = -1e30f;
#pragma unroll
    for (int c = 0; c < 21; c++) {
      s[c] = score[(size_t)t * 128 + c] * (1.f / 49.f);
      mx = fmaxf(mx, s[c]);
    }
    float sum = 0.f;
#pragma unroll
    for (int c = 0; c < 21; c++) { s[c] = expf(s[c] - mx); sum += s[c]; }
    float rs = 1.f / sum;
#pragma unroll
    for (int c = 0; c < 21; c++) out[(size_t)t * 21 + c] = s[c] * rs;
  }
  if (t < 100800) {
    int roi = t / 84, c = t - (t / 84) * 84;
    out[25200 + t] = score[(size_t)roi * 128 + 21 + c] * (1.f / 49.f);
  }
}

extern "C" void kernel_launch(void* const* d_in, const int* in_sizes, int n_in,
                              void* d_out, int out_size, void* d_ws, size_t ws_size,
                              hipStream_t stream) {
  const float* base_feat = (const float*)d_in[0];
  const float* rois      = (const float*)d_in[1];
  const float* w_conv1   = (const float*)d_in[2];
  const float* w_cls     = (const float*)d_in[3];
  const float* w_bbox    = (const float*)d_in[4];
  float* out = (float*)d_out;
  char* ws = (char*)d_ws;

  unsigned short* featT = (unsigned short*)(ws + OFF_FEATT);
  unsigned short* w1b   = (unsigned short*)(ws + OFF_W1);
  unsigned short* Wc    = (unsigned short*)(ws + OFF_WC);
  int*            desc  = (int*)(ws + OFF_DESC);
  float*          score = (float*)(ws + OFF_SCORE);
  float*          X     = (float*)(ws + OFF_X);
  float*          S1    = (float*)(ws + OFF_FEATT);  // aliases featT (dead after GEMM)
  float*          Sf    = X;                          // vscan overwrites X (disjoint pass)
  unsigned short* U     = (unsigned short*)(ws + OFF_U);
  unsigned short* P     = (unsigned short*)(ws + OFF_P);

  k_cvt_w1<<<2048, 256, 0, stream>>>(w_conv1, w1b);
  k_cvt_wcomb<<<6272, 256, 0, stream>>>(w_cls, w_bbox, Wc);
  k_tpose<<<dim3(64, 32, 4), 256, 0, stream>>>(base_feat, featT);
  k_gemm_conv1<<<dim3(32, 8, 4), 256, 0, stream>>>((const short*)featT, (const short*)w1b, X);
  k_hscan<<<1024, 256, 0, stream>>>(X, S1);
  k_vscan<<<1024, 256, 0, stream>>>(S1, Sf);
  k_desc<<<245, 256, 0, stream>>>(rois, desc);
  for (int h = 0; h < 2; h++) {
    k_ubuild<<<640 * 49, 256, 0, stream>>>(Sf, desc + (size_t)h * 640 * 49 * 8, U);
    k_poolgemm2<<<dim3(10, 49), 256, 0, stream>>>(U, Wc, P);
    k_reduce<<<280, 256, 0, stream>>>(P, score + (size_t)h * 640 * 128);
  }
  k_final<<<394, 256, 0, stream>>>(score, out);
}

// Round 3
// 515.677 us; speedup vs baseline: 1.1107x; 1.0434x over previous
//
#include <hip/hip_runtime.h>
#include <cstdint>

// ---------------------------------------------------------------------------
// R-FCN head on MI355X.  Round 3: XOR-swizzled LDS-image layouts.
// global_load_lds forces As/Bs rows contiguous (128B = 32-bank stride), so
// MFMA fragment reads were up to 16-way bank-conflicted (2.5e7 conflict
// cycles on conv1). Fix: pre-swizzle featT/w1b/U/Wc in GLOBAL memory —
// within each 64-elem k-chunk, 16B group g is stored at g ^ (row&7).
// Fragment reads use ko = ((kt*4 + (lane>>4)) ^ (lane&7)) * 8.
// ---------------------------------------------------------------------------

typedef __attribute__((ext_vector_type(8))) short short8;   // 8 bf16 (4 VGPRs)
typedef __attribute__((ext_vector_type(4))) short short4v;
typedef __attribute__((ext_vector_type(4))) float f32x4;

// workspace layout (bytes)
#define OFF_FEATT 0ull          // bf16 [4][4096][2048] = 67108864 ; later S1 f32; later U+P
#define OFF_W1    67108864ull   // bf16 [1024][2048]    = 4194304  (dead after conv1)
#define OFF_U     0ull          // bf16 [640][49][1024] = 64225280
#define OFF_P     64225280ull   // bf16 [49][640][112]  = 7024640  (ends 71249920 <= 71303168)
#define OFF_WC    71303168ull   // bf16 [128][49][1024] = 12845056 (rows 105..127 zero)
#define OFF_DESC  84148224ull   // int  [1280][49][8]   = 2007040
#define OFF_SCORE 86155264ull   // f32  [1280][128]     = 655360
#define OFF_X     86810624ull   // f32  [4][4096][1024] = 67108864 (X, then Sf)
// total 153,919,488 bytes

__device__ __forceinline__ unsigned short f2bf(float f) {
  unsigned u = __float_as_uint(f);
  u += 0x7fffu + ((u >> 16) & 1u);        // round-to-nearest-even
  return (unsigned short)(u >> 16);
}
__device__ __forceinline__ float bf2f(unsigned short h) {
  return __uint_as_float(((unsigned)h) << 16);
}

// swizzle low-6-bits of a k index: 16B group g (bits 3..5) -> g ^ key
__device__ __forceinline__ int swz6(int k6, int key) {
  return ((((k6 >> 3) & 7) ^ key) << 3) | (k6 & 7);
}

__device__ __forceinline__ void gload16(const void* g, void* l) {
  __builtin_amdgcn_global_load_lds((const __attribute__((address_space(1))) void*)g,
                                   (__attribute__((address_space(3))) void*)l, 16, 0, 0);
}

// --- weight conversions ----------------------------------------------------
__global__ __launch_bounds__(256) void k_cvt_w1(const float* __restrict__ src,
                                                unsigned short* __restrict__ dst) {
  int t = blockIdx.x * 256 + threadIdx.x;
  long e = (long)t * 4;
  if (e >= 1024 * 2048) return;
  int o = (int)(e >> 11), k = (int)(e & 2047);
  float4 q = *(const float4*)(src + e);
  short4v s = {(short)f2bf(q.x), (short)f2bf(q.y), (short)f2bf(q.z), (short)f2bf(q.w)};
  int kp = (k & ~63) | swz6(k & 63, o & 7);
  *(short4v*)(dst + (size_t)o * 2048 + kp) = s;
}

// Wc[c][ij][k]: c<21 -> w_cls[c*49+ij], c<105 -> w_bbox[(c-21)*49+ij], else 0
__global__ __launch_bounds__(256) void k_cvt_wcomb(const float* __restrict__ wcls,
                                                   const float* __restrict__ wbbox,
                                                   unsigned short* __restrict__ dst) {
  int t = blockIdx.x * 256 + threadIdx.x;
  if (t >= 128 * 49 * 256) return;
  size_t e = (size_t)t * 4;
  int c = (int)(e / 50176);
  int rem = (int)(e - (size_t)c * 50176);
  int ij = rem >> 10, k = rem & 1023;
  float4 q = make_float4(0.f, 0.f, 0.f, 0.f);
  if (c < 21)       q = *(const float4*)(wcls + (size_t)(c * 49 + ij) * 1024 + k);
  else if (c < 105) q = *(const float4*)(wbbox + (size_t)((c - 21) * 49 + ij) * 1024 + k);
  short4v s = {(short)f2bf(q.x), (short)f2bf(q.y), (short)f2bf(q.z), (short)f2bf(q.w)};
  int kp = (k & ~63) | swz6(k & 63, c & 7);
  *(short4v*)(dst + ((size_t)(c * 49 + ij) * 1024 + kp)) = s;
}

// --- base_feat [b][c][s] fp32 -> featT [b][s][c] bf16 (swizzled) -----------
__global__ __launch_bounds__(256) void k_tpose(const float* __restrict__ src,
                                               unsigned short* __restrict__ dst) {
  __shared__ float tile[64][65];
  int s0 = blockIdx.x * 64, c0 = blockIdx.y * 64, b = blockIdx.z;
  int tx = threadIdx.x & 63, ty = threadIdx.x >> 6;
  const float* sp = src + ((size_t)b * 2048 + c0) * 4096 + s0;
#pragma unroll
  for (int i = 0; i < 16; i++) {
    int cl = ty * 16 + i;
    tile[cl][tx] = sp[(size_t)cl * 4096 + tx];
  }
  __syncthreads();
  unsigned short* dp = dst + ((size_t)b * 4096 + s0) * 2048 + c0;
#pragma unroll
  for (int i = 0; i < 16; i++) {
    int sl = ty * 16 + i;               // spatial row (s0+sl); key = sl&7
    dp[(size_t)sl * 2048 + swz6(tx, sl & 7)] = f2bf(tile[tx][sl]);
  }
}

// --- conv1: X[b][s][o] = relu(sum_k featT[b][s][k] * w1[o][k]) -------------
__global__ __launch_bounds__(256) void k_gemm_conv1(const short* __restrict__ A,
                                                    const short* __restrict__ Bw,
                                                    float* __restrict__ X) {
  int mt = blockIdx.x, nt = blockIdx.y, b = blockIdx.z;
  __shared__ short As[128 * 64];   // [m][k] rows k-contiguous (swizzled image)
  __shared__ short Bs[128 * 64];   // [n][k]
  int tid = threadIdx.x, lane = tid & 63, wave = tid >> 6;
  int wm = wave >> 1, wn = wave & 1;
  f32x4 acc[4][4];
#pragma unroll
  for (int i = 0; i < 4; i++)
#pragma unroll
    for (int j = 0; j < 4; j++) acc[i][j] = (f32x4){0.f, 0.f, 0.f, 0.f};

  const short* Ab = A + ((size_t)b * 4096 + (size_t)mt * 128) * 2048;
  const short* Bb = Bw + (size_t)nt * 128 * 2048;
  int lr = lane >> 3;          // row within 8-row chunk
  int lc = (lane & 7) * 8;     // k element
  int key = lane & 7;

  for (int k0 = 0; k0 < 2048; k0 += 64) {
#pragma unroll
    for (int i = 0; i < 4; i++) {
      int row = i * 32 + wave * 8 + lr;
      gload16(Ab + (size_t)row * 2048 + k0 + lc, (char*)As + (i * 32 + wave * 8) * 128);
      gload16(Bb + (size_t)row * 2048 + k0 + lc, (char*)Bs + (i * 32 + wave * 8) * 128);
    }
    __syncthreads();
#pragma unroll
    for (int kt = 0; kt < 2; kt++) {
      int ko = (((kt << 2) | (lane >> 4)) ^ key) << 3;   // swizzled fragment offset
      short8 af[4], bfr[4];
#pragma unroll
      for (int i = 0; i < 4; i++)
        af[i] = *(const short8*)(As + (wm * 64 + i * 16 + (lane & 15)) * 64 + ko);
#pragma unroll
      for (int j = 0; j < 4; j++)
        bfr[j] = *(const short8*)(Bs + (wn * 64 + j * 16 + (lane & 15)) * 64 + ko);
#pragma unroll
      for (int i = 0; i < 4; i++)
#pragma unroll
        for (int j = 0; j < 4; j++)
          acc[i][j] = __builtin_amdgcn_mfma_f32_16x16x32_bf16(af[i], bfr[j], acc[i][j], 0, 0, 0);
    }
    __syncthreads();
  }
  float* Xb = X + ((size_t)b * 4096 + (size_t)mt * 128) * 1024 + nt * 128;
#pragma unroll
  for (int i = 0; i < 4; i++)
#pragma unroll
    for (int j = 0; j < 4; j++) {
      int row = wm * 64 + i * 16 + (lane >> 4) * 4;
      int col = wn * 64 + j * 16 + (lane & 15);
#pragma unroll
      for (int r = 0; r < 4; r++)
        Xb[(size_t)(row + r) * 1024 + col] = fmaxf(acc[i][j][r], 0.f);
    }
}

// --- integral image: horizontal then vertical inclusive scans --------------
__global__ __launch_bounds__(256) void k_hscan(const float* __restrict__ X,
                                               float* __restrict__ S1) {
  int t = blockIdx.x * 256 + threadIdx.x;   // [0, 4*64*1024)
  int c = t & 1023;
  int bh = t >> 10;                          // b*64 + h
  size_t base = (size_t)bh * 64 * 1024 + c;
  float acc = 0.f;
  for (int w = 0; w < 64; w++) {
    size_t idx = base + (size_t)w * 1024;
    acc += X[idx];
    S1[idx] = acc;
  }
}
__global__ __launch_bounds__(256) void k_vscan(const float* __restrict__ S1,
                                               float* __restrict__ Sf) {
  int t = blockIdx.x * 256 + threadIdx.x;
  int c = t & 1023;
  int bw = t >> 10;
  int b = bw >> 6, w = bw & 63;
  size_t base = ((size_t)b * 4096 + w) * 1024 + c;
  float acc = 0.f;
  for (int h = 0; h < 64; h++) {
    size_t idx = base + (size_t)h * 64 * 1024;
    acc += S1[idx];
    Sf[idx] = acc;
  }
}

// --- per-(roi,bin) descriptors: 4 corner offsets + 1/area ------------------
__global__ __launch_bounds__(256) void k_desc(const float* __restrict__ rois,
                                              int* __restrict__ desc) {
  int t = blockIdx.x * 256 + threadIdx.x;
  if (t >= 1280 * 49) return;
  int roi = t / 49, ij = t - roi * 49;
  int* d = desc + (size_t)t * 8;
  if (roi >= 1200) { d[0] = d[1] = d[2] = d[3] = -1; d[4] = 0; return; }
  const float* r = rois + (size_t)roi * 5;
  int b = (int)r[0];
  float x1 = __fmul_rn(floorf(__fadd_rn(r[1], 0.5f)), 0.0625f);
  float y1 = __fmul_rn(floorf(__fadd_rn(r[2], 0.5f)), 0.0625f);
  float x2 = __fmul_rn(floorf(__fadd_rn(__fadd_rn(r[3], 1.0f), 0.5f)), 0.0625f);
  float y2 = __fmul_rn(floorf(__fadd_rn(__fadd_rn(r[4], 1.0f), 0.5f)), 0.0625f);
  float bw = __fdiv_rn(fmaxf(__fsub_rn(x2, x1), 0.1f), 7.0f);
  float bh = __fdiv_rn(fmaxf(__fsub_rn(y2, y1), 0.1f), 7.0f);
  int i = ij / 7, j = ij - (ij / 7) * 7;
  float fi = (float)i, fj = (float)j;
  int hs = (int)fminf(fmaxf(floorf(__fadd_rn(__fmul_rn(fi, bh), y1)), 0.f), 64.f);
  int he = (int)fminf(fmaxf(ceilf(__fadd_rn(__fmul_rn(__fadd_rn(fi, 1.f), bh), y1)), 0.f), 64.f);
  int wsx = (int)fminf(fmaxf(floorf(__fadd_rn(__fmul_rn(fj, bw), x1)), 0.f), 64.f);
  int we = (int)fminf(fmaxf(ceilf(__fadd_rn(__fmul_rn(__fadd_rn(fj, 1.f), bw), x1)), 0.f), 64.f);
  int dh = max(he - hs, 0), dw = max(we - wsx, 0);
  float inv = (dh * dw > 0) ? 1.0f / (float)(dh * dw) : 0.f;
  auto off = [&](int h, int w) -> int {
    return (h > 0 && w > 0) ? (((b * 64 + (h - 1)) * 64 + (w - 1)) * 1024) : -1;
  };
  d[0] = off(he, we);   // +
  d[1] = off(hs, we);   // -
  d[2] = off(he, wsx);  // -
  d[3] = off(hs, wsx);  // +
  ((float*)d)[4] = inv;
}

// --- u-build: U[roi_local][ij][k] bf16 (swizzled) --------------------------
__global__ __launch_bounds__(256) void k_ubuild(const float* __restrict__ Sf,
                                                const int* __restrict__ desc,
                                                unsigned short* __restrict__ U) {
  int t = blockIdx.x;                 // roi_local*49 + ij
  const int* d = desc + (size_t)t * 8;
  int o0 = d[0], o1 = d[1], o2 = d[2], o3 = d[3];
  float inv = ((const float*)d)[4];
  int key = (t / 49) & 7;             // roi_local & 7
  int k = threadIdx.x * 4;
  float ax = 0.f, ay = 0.f, az = 0.f, aw = 0.f;
  if (o0 >= 0) { float4 q = *(const float4*)(Sf + o0 + k); ax += q.x; ay += q.y; az += q.z; aw += q.w; }
  if (o1 >= 0) { float4 q = *(const float4*)(Sf + o1 + k); ax -= q.x; ay -= q.y; az -= q.z; aw -= q.w; }
  if (o2 >= 0) { float4 q = *(const float4*)(Sf + o2 + k); ax -= q.x; ay -= q.y; az -= q.z; aw -= q.w; }
  if (o3 >= 0) { float4 q = *(const float4*)(Sf + o3 + k); ax += q.x; ay += q.y; az += q.z; aw += q.w; }
  short4v s = {(short)f2bf(ax * inv), (short)f2bf(ay * inv),
               (short)f2bf(az * inv), (short)f2bf(aw * inv)};
  int kp = (k & ~63) | swz6(k & 63, key);
  *(short4v*)(U + (size_t)t * 1024 + kp) = s;
}

// --- pool-GEMM (per 640-roi half): P[ij][roi][c] = sum_k U*Wc --------------
__global__ __launch_bounds__(256) void k_poolgemm2(const unsigned short* __restrict__ U,
                                                   const unsigned short* __restrict__ Wc,
                                                   unsigned short* __restrict__ P) {
  int mt = blockIdx.x;   // 0..9 (64-roi tile)
  int ij = blockIdx.y;   // 0..48
  __shared__ short As[64 * 64];    // [roi][k] bf16 (swizzled image)
  __shared__ short Bs[128 * 64];   // [c][k]
  int tid = threadIdx.x, lane = tid & 63, wave = tid >> 6;
  f32x4 acc[4][2];
#pragma unroll
  for (int i = 0; i < 4; i++)
#pragma unroll
    for (int j = 0; j < 2; j++) acc[i][j] = (f32x4){0.f, 0.f, 0.f, 0.f};

  const unsigned short* Ab = U + ((size_t)mt * 64 * 49 + ij) * 1024;
  const unsigned short* Bb = Wc + (size_t)ij * 1024;
  int lr = lane >> 3, lc = (lane & 7) * 8;
  int key = lane & 7;

  for (int k0 = 0; k0 < 1024; k0 += 64) {
#pragma unroll
    for (int i = 0; i < 2; i++) {
      int row = i * 32 + wave * 8 + lr;
      gload16(Ab + (size_t)row * (49 * 1024) + k0 + lc, (char*)As + (i * 32 + wave * 8) * 128);
    }
#pragma unroll
    for (int i = 0; i < 4; i++) {
      int row = i * 32 + wave * 8 + lr;
      gload16(Bb + (size_t)row * (49 * 1024) + k0 + lc, (char*)Bs + (i * 32 + wave * 8) * 128);
    }
    __syncthreads();
#pragma unroll
    for (int kt = 0; kt < 2; kt++) {
      int ko = (((kt << 2) | (lane >> 4)) ^ key) << 3;
      short8 af[4], bfr[2];
#pragma unroll
      for (int i = 0; i < 4; i++)
        af[i] = *(const short8*)(As + (i * 16 + (lane & 15)) * 64 + ko);
#pragma unroll
      for (int j = 0; j < 2; j++)
        bfr[j] = *(const short8*)(Bs + (wave * 32 + j * 16 + (lane & 15)) * 64 + ko);
#pragma unroll
      for (int i = 0; i < 4; i++)
#pragma unroll
        for (int j = 0; j < 2; j++)
          acc[i][j] = __builtin_amdgcn_mfma_f32_16x16x32_bf16(af[i], bfr[j], acc[i][j], 0, 0, 0);
    }
    __syncthreads();
  }
  // store partials P[ij][640][112] bf16 (c>=112 dropped; only c<105 used)
  unsigned short* Pb = P + (size_t)ij * 640 * 112;
#pragma unroll
  for (int i = 0; i < 4; i++)
#pragma unroll
    for (int j = 0; j < 2; j++) {
      int cc = wave * 32 + j * 16 + (lane & 15);
      if (cc < 112) {
        int rbase = mt * 64 + i * 16 + (lane >> 4) * 4;
#pragma unroll
        for (int r = 0; r < 4; r++)
          Pb[(size_t)(rbase + r) * 112 + cc] = f2bf(acc[i][j][r]);
      }
    }
}

// --- reduce 49 ij-partials -> score (per half) -----------------------------
__global__ __launch_bounds__(256) void k_reduce(const unsigned short* __restrict__ P,
                                                float* __restrict__ score) {
  int t = blockIdx.x * 256 + threadIdx.x;   // 640*112
  if (t >= 640 * 112) return;
  int roi = t / 112, c = t - roi * 112;
  float s = 0.f;
#pragma unroll 7
  for (int ij = 0; ij < 49; ij++) s += bf2f(P[(size_t)ij * 640 * 112 + t]);
  score[(size_t)roi * 128 + c] = s;
}

// --- epilogue: softmax(cls/49) + bbox/49 -----------------------------------
__global__ __launch_bounds__(256) void k_final(const float* __restrict__ score,
                                               float* __restrict__ out) {
  int t = blockIdx.x * 256 + threadIdx.x;
  if (t < 1200) {
    float s[21];
    float mx = -1e30f;
#pragma unroll
    for (int c = 0; c < 21; c++) {
      s[c] = score[(size_t)t * 128 + c] * (1.f / 49.f);
      mx = fmaxf(mx, s[c]);
    }
    float sum = 0.f;
#pragma unroll
    for (int c = 0; c < 21; c++) { s[c] = expf(s[c] - mx); sum += s[c]; }
    float rs = 1.f / sum;
#pragma unroll
    for (int c = 0; c < 21; c++) out[(size_t)t * 21 + c] = s[c] * rs;
  }
  if (t < 100800) {
    int roi = t / 84, c = t - (t / 84) * 84;
    out[25200 + t] = score[(size_t)roi * 128 + 21 + c] * (1.f / 49.f);
  }
}

extern "C" void kernel_launch(void* const* d_in, const int* in_sizes, int n_in,
                              void* d_out, int out_size, void* d_ws, size_t ws_size,
                              hipStream_t stream) {
  const float* base_feat = (const float*)d_in[0];
  const float* rois      = (const float*)d_in[1];
  const float* w_conv1   = (const float*)d_in[2];
  const float* w_cls     = (const float*)d_in[3];
  const float* w_bbox    = (const float*)d_in[4];
  float* out = (float*)d_out;
  char* ws = (char*)d_ws;

  unsigned short* featT = (unsigned short*)(ws + OFF_FEATT);
  unsigned short* w1b   = (unsigned short*)(ws + OFF_W1);
  unsigned short* Wc    = (unsigned short*)(ws + OFF_WC);
  int*            desc  = (int*)(ws + OFF_DESC);
  float*          score = (float*)(ws + OFF_SCORE);
  float*          X     = (float*)(ws + OFF_X);
  float*          S1    = (float*)(ws + OFF_FEATT);  // aliases featT (dead after GEMM)
  float*          Sf    = X;                          // vscan overwrites X (disjoint pass)
  unsigned short* U     = (unsigned short*)(ws + OFF_U);
  unsigned short* P     = (unsigned short*)(ws + OFF_P);

  k_cvt_w1<<<2048, 256, 0, stream>>>(w_conv1, w1b);
  k_cvt_wcomb<<<6272, 256, 0, stream>>>(w_cls, w_bbox, Wc);
  k_tpose<<<dim3(64, 32, 4), 256, 0, stream>>>(base_feat, featT);
  k_gemm_conv1<<<dim3(32, 8, 4), 256, 0, stream>>>((const short*)featT, (const short*)w1b, X);
  k_hscan<<<1024, 256, 0, stream>>>(X, S1);
  k_vscan<<<1024, 256, 0, stream>>>(S1, Sf);
  k_desc<<<245, 256, 0, stream>>>(rois, desc);
  for (int h = 0; h < 2; h++) {
    k_ubuild<<<640 * 49, 256, 0, stream>>>(Sf, desc + (size_t)h * 640 * 49 * 8, U);
    k_poolgemm2<<<dim3(10, 49), 256, 0, stream>>>(U, Wc, P);
    k_reduce<<<280, 256, 0, stream>>>(P, score + (size_t)h * 640 * 128);
  }
  k_final<<<394, 256, 0, stream>>>(score, out);
}

// Round 4
// 434.595 us; speedup vs baseline: 1.3179x; 1.1866x over previous
//
#include <hip/hip_runtime.h>
#include <cstdint>

// ---------------------------------------------------------------------------
// R-FCN head on MI355X.  Round 4:
//  - DROP integral image (rois are 1-10 cells; bins 1-3 cells): k_ubuild does
//    direct bin summation over X (dh*dw ~2-3 reads vs 4 scattered corners),
//    deleting k_hscan/k_vscan (-268MB traffic, -2 dispatches), better L2
//    locality, better numerics.
//  - Single-pass pool chain when ws_size >= 296.5MB (branch on ws_size is
//    call-invariant -> graph-safe); else 2-half fallback.
//  - tpose: 4-wide (8B) bf16 stores instead of scalar.
//  XOR-swizzled LDS-image layouts retained (round-3 win, conflicts = 0).
// ---------------------------------------------------------------------------

typedef __attribute__((ext_vector_type(8))) short short8;   // 8 bf16 (4 VGPRs)
typedef __attribute__((ext_vector_type(4))) short short4v;
typedef __attribute__((ext_vector_type(4))) float f32x4;

// workspace layout (bytes)
#define OFF_FEATT 0ull          // bf16 [4][4096][2048] = 67108864 ; later U+P (2-half path)
#define OFF_W1    67108864ull   // bf16 [1024][2048]    = 4194304  (dead after conv1)
#define OFF_U2    0ull          // bf16 [640][49][1024] = 64225280   (2-half)
#define OFF_P2    64225280ull   // bf16 [49][640][112]  = 7024640  -> 71249920 <= 71303168
#define OFF_WC    71303168ull   // bf16 [128][49][1024] = 12845056 (rows 105..127 zero)
#define OFF_DESC  84148224ull   // int  [1280][49][8]   = 2007040
#define OFF_SCORE 86155264ull   // f32  [1280][128]     = 655360
#define OFF_X     86810624ull   // f32  [4][4096][1024] = 67108864 -> ends 153919488
#define OFF_U1    153919488ull  // bf16 [1280][49][1024] = 128450560 (1-pass)
#define OFF_P1    282370048ull  // bf16 [49][1280][112]  = 14049280 -> ends 296419328
#define ONEPASS_BYTES 296419328ull

__device__ __forceinline__ unsigned short f2bf(float f) {
  unsigned u = __float_as_uint(f);
  u += 0x7fffu + ((u >> 16) & 1u);        // round-to-nearest-even
  return (unsigned short)(u >> 16);
}
__device__ __forceinline__ float bf2f(unsigned short h) {
  return __uint_as_float(((unsigned)h) << 16);
}

// swizzle low-6-bits of a k index: 16B group g (bits 3..5) -> g ^ key
__device__ __forceinline__ int swz6(int k6, int key) {
  return ((((k6 >> 3) & 7) ^ key) << 3) | (k6 & 7);
}

__device__ __forceinline__ void gload16(const void* g, void* l) {
  __builtin_amdgcn_global_load_lds((const __attribute__((address_space(1))) void*)g,
                                   (__attribute__((address_space(3))) void*)l, 16, 0, 0);
}

// --- weight conversions ----------------------------------------------------
__global__ __launch_bounds__(256) void k_cvt_w1(const float* __restrict__ src,
                                                unsigned short* __restrict__ dst) {
  int t = blockIdx.x * 256 + threadIdx.x;
  long e = (long)t * 4;
  if (e >= 1024 * 2048) return;
  int o = (int)(e >> 11), k = (int)(e & 2047);
  float4 q = *(const float4*)(src + e);
  short4v s = {(short)f2bf(q.x), (short)f2bf(q.y), (short)f2bf(q.z), (short)f2bf(q.w)};
  int kp = (k & ~63) | swz6(k & 63, o & 7);
  *(short4v*)(dst + (size_t)o * 2048 + kp) = s;
}

// Wc[c][ij][k]: c<21 -> w_cls[c*49+ij], c<105 -> w_bbox[(c-21)*49+ij], else 0
__global__ __launch_bounds__(256) void k_cvt_wcomb(const float* __restrict__ wcls,
                                                   const float* __restrict__ wbbox,
                                                   unsigned short* __restrict__ dst) {
  int t = blockIdx.x * 256 + threadIdx.x;
  if (t >= 128 * 49 * 256) return;
  size_t e = (size_t)t * 4;
  int c = (int)(e / 50176);
  int rem = (int)(e - (size_t)c * 50176);
  int ij = rem >> 10, k = rem & 1023;
  float4 q = make_float4(0.f, 0.f, 0.f, 0.f);
  if (c < 21)       q = *(const float4*)(wcls + (size_t)(c * 49 + ij) * 1024 + k);
  else if (c < 105) q = *(const float4*)(wbbox + (size_t)((c - 21) * 49 + ij) * 1024 + k);
  short4v s = {(short)f2bf(q.x), (short)f2bf(q.y), (short)f2bf(q.z), (short)f2bf(q.w)};
  int kp = (k & ~63) | swz6(k & 63, c & 7);
  *(short4v*)(dst + ((size_t)(c * 49 + ij) * 1024 + kp)) = s;
}

// --- base_feat [b][c][s] fp32 -> featT [b][s][c] bf16 (swizzled) -----------
__global__ __launch_bounds__(256) void k_tpose(const float* __restrict__ src,
                                               unsigned short* __restrict__ dst) {
  __shared__ float tile[64][65];
  int s0 = blockIdx.x * 64, c0 = blockIdx.y * 64, b = blockIdx.z;
  int tx = threadIdx.x & 63, ty = threadIdx.x >> 6;
  const float* sp = src + ((size_t)b * 2048 + c0) * 4096 + s0;
#pragma unroll
  for (int i = 0; i < 16; i++) {
    int cl = ty * 16 + i;
    tile[cl][tx] = sp[(size_t)cl * 4096 + tx];
  }
  __syncthreads();
  unsigned short* dp = dst + ((size_t)b * 4096 + s0) * 2048 + c0;
  int c4 = (threadIdx.x & 15) * 4;      // channel start (within 64-chunk)
  int sy = threadIdx.x >> 4;            // spatial row
#pragma unroll
  for (int i = 0; i < 4; i++) {
    int sl = i * 16 + sy;
    int key = sl & 7;
    short4v v = {(short)f2bf(tile[c4 + 0][sl]), (short)f2bf(tile[c4 + 1][sl]),
                 (short)f2bf(tile[c4 + 2][sl]), (short)f2bf(tile[c4 + 3][sl])};
    *(short4v*)(dp + (size_t)sl * 2048 + swz6(c4, key)) = v;  // 8B store, same group
  }
}

// --- conv1: X[b][s][o] = relu(sum_k featT[b][s][k] * w1[o][k]) -------------
__global__ __launch_bounds__(256) void k_gemm_conv1(const short* __restrict__ A,
                                                    const short* __restrict__ Bw,
                                                    float* __restrict__ X) {
  int mt = blockIdx.x, nt = blockIdx.y, b = blockIdx.z;
  __shared__ short As[128 * 64];   // [m][k] rows k-contiguous (swizzled image)
  __shared__ short Bs[128 * 64];   // [n][k]
  int tid = threadIdx.x, lane = tid & 63, wave = tid >> 6;
  int wm = wave >> 1, wn = wave & 1;
  f32x4 acc[4][4];
#pragma unroll
  for (int i = 0; i < 4; i++)
#pragma unroll
    for (int j = 0; j < 4; j++) acc[i][j] = (f32x4){0.f, 0.f, 0.f, 0.f};

  const short* Ab = A + ((size_t)b * 4096 + (size_t)mt * 128) * 2048;
  const short* Bb = Bw + (size_t)nt * 128 * 2048;
  int lr = lane >> 3;          // row within 8-row chunk
  int lc = (lane & 7) * 8;     // k element
  int key = lane & 7;

  for (int k0 = 0; k0 < 2048; k0 += 64) {
#pragma unroll
    for (int i = 0; i < 4; i++) {
      int row = i * 32 + wave * 8 + lr;
      gload16(Ab + (size_t)row * 2048 + k0 + lc, (char*)As + (i * 32 + wave * 8) * 128);
      gload16(Bb + (size_t)row * 2048 + k0 + lc, (char*)Bs + (i * 32 + wave * 8) * 128);
    }
    __syncthreads();
#pragma unroll
    for (int kt = 0; kt < 2; kt++) {
      int ko = (((kt << 2) | (lane >> 4)) ^ key) << 3;   // swizzled fragment offset
      short8 af[4], bfr[4];
#pragma unroll
      for (int i = 0; i < 4; i++)
        af[i] = *(const short8*)(As + (wm * 64 + i * 16 + (lane & 15)) * 64 + ko);
#pragma unroll
      for (int j = 0; j < 4; j++)
        bfr[j] = *(const short8*)(Bs + (wn * 64 + j * 16 + (lane & 15)) * 64 + ko);
#pragma unroll
      for (int i = 0; i < 4; i++)
#pragma unroll
        for (int j = 0; j < 4; j++)
          acc[i][j] = __builtin_amdgcn_mfma_f32_16x16x32_bf16(af[i], bfr[j], acc[i][j], 0, 0, 0);
    }
    __syncthreads();
  }
  float* Xb = X + ((size_t)b * 4096 + (size_t)mt * 128) * 1024 + nt * 128;
#pragma unroll
  for (int i = 0; i < 4; i++)
#pragma unroll
    for (int j = 0; j < 4; j++) {
      int row = wm * 64 + i * 16 + (lane >> 4) * 4;
      int col = wn * 64 + j * 16 + (lane & 15);
#pragma unroll
      for (int r = 0; r < 4; r++)
        Xb[(size_t)(row + r) * 1024 + col] = fmaxf(acc[i][j][r], 0.f);
    }
}

// --- per-(roi,bin) descriptors: batch, bin rect, 1/area --------------------
// fp32 ops mirror the reference exactly (unfused mul/add, floor/ceil, clip)
__global__ __launch_bounds__(256) void k_desc(const float* __restrict__ rois,
                                              int* __restrict__ desc) {
  int t = blockIdx.x * 256 + threadIdx.x;
  if (t >= 1280 * 49) return;
  int roi = t / 49, ij = t - roi * 49;
  int* d = desc + (size_t)t * 8;
  if (roi >= 1200) { d[0] = 0; d[1] = 0; d[2] = 0; d[3] = 0; d[4] = 0; ((float*)d)[5] = 0.f; return; }
  const float* r = rois + (size_t)roi * 5;
  int b = (int)r[0];
  float x1 = __fmul_rn(floorf(__fadd_rn(r[1], 0.5f)), 0.0625f);
  float y1 = __fmul_rn(floorf(__fadd_rn(r[2], 0.5f)), 0.0625f);
  float x2 = __fmul_rn(floorf(__fadd_rn(__fadd_rn(r[3], 1.0f), 0.5f)), 0.0625f);
  float y2 = __fmul_rn(floorf(__fadd_rn(__fadd_rn(r[4], 1.0f), 0.5f)), 0.0625f);
  float bw = __fdiv_rn(fmaxf(__fsub_rn(x2, x1), 0.1f), 7.0f);
  float bh = __fdiv_rn(fmaxf(__fsub_rn(y2, y1), 0.1f), 7.0f);
  int i = ij / 7, j = ij - (ij / 7) * 7;
  float fi = (float)i, fj = (float)j;
  int hs = (int)fminf(fmaxf(floorf(__fadd_rn(__fmul_rn(fi, bh), y1)), 0.f), 64.f);
  int he = (int)fminf(fmaxf(ceilf(__fadd_rn(__fmul_rn(__fadd_rn(fi, 1.f), bh), y1)), 0.f), 64.f);
  int wsx = (int)fminf(fmaxf(floorf(__fadd_rn(__fmul_rn(fj, bw), x1)), 0.f), 64.f);
  int we = (int)fminf(fmaxf(ceilf(__fadd_rn(__fmul_rn(__fadd_rn(fj, 1.f), bw), x1)), 0.f), 64.f);
  int dh = max(he - hs, 0), dw = max(we - wsx, 0);
  float inv = (dh * dw > 0) ? 1.0f / (float)(dh * dw) : 0.f;
  d[0] = b; d[1] = hs; d[2] = he; d[3] = wsx; d[4] = we;
  ((float*)d)[5] = inv;
}

// --- u-build: direct bin sum over X, bf16 swizzled output ------------------
// One block per (roi,ij); thread k-chunk of 4. dh*dw in [0,9], typically 2-3.
__global__ __launch_bounds__(256) void k_ubuild(const float* __restrict__ X,
                                                const int* __restrict__ desc,
                                                unsigned short* __restrict__ U) {
  int t = blockIdx.x;                 // roi_local*49 + ij
  const int* d = desc + (size_t)t * 8;
  int b = d[0], hs = d[1], he = d[2], wsx = d[3], we = d[4];
  float inv = ((const float*)d)[5];
  int key = (t / 49) & 7;             // roi & 7
  int k = threadIdx.x * 4;
  float ax = 0.f, ay = 0.f, az = 0.f, aw = 0.f;
  for (int h = hs; h < he; h++) {
    const float* rowp = X + ((size_t)((b * 64 + h) * 64 + wsx)) * 1024 + k;
    for (int w = wsx; w < we; w++) {
      float4 q = *(const float4*)rowp;
      ax += q.x; ay += q.y; az += q.z; aw += q.w;
      rowp += 1024;
    }
  }
  short4v s = {(short)f2bf(ax * inv), (short)f2bf(ay * inv),
               (short)f2bf(az * inv), (short)f2bf(aw * inv)};
  int kp = (k & ~63) | swz6(k & 63, key);
  *(short4v*)(U + (size_t)t * 1024 + kp) = s;
}

// --- pool-GEMM: P[ij][roi][c] = sum_k U[roi][ij][k] * Wc[c][ij][k] ---------
__global__ __launch_bounds__(256) void k_poolgemm2(const unsigned short* __restrict__ U,
                                                   const unsigned short* __restrict__ Wc,
                                                   unsigned short* __restrict__ P,
                                                   int nroi) {
  int mt = blockIdx.x;   // 64-roi tile
  int ij = blockIdx.y;   // 0..48
  __shared__ short As[64 * 64];    // [roi][k] bf16 (swizzled image)
  __shared__ short Bs[128 * 64];   // [c][k]
  int tid = threadIdx.x, lane = tid & 63, wave = tid >> 6;
  f32x4 acc[4][2];
#pragma unroll
  for (int i = 0; i < 4; i++)
#pragma unroll
    for (int j = 0; j < 2; j++) acc[i][j] = (f32x4){0.f, 0.f, 0.f, 0.f};

  const unsigned short* Ab = U + ((size_t)mt * 64 * 49 + ij) * 1024;
  const unsigned short* Bb = Wc + (size_t)ij * 1024;
  int lr = lane >> 3, lc = (lane & 7) * 8;
  int key = lane & 7;

  for (int k0 = 0; k0 < 1024; k0 += 64) {
#pragma unroll
    for (int i = 0; i < 2; i++) {
      int row = i * 32 + wave * 8 + lr;
      gload16(Ab + (size_t)row * (49 * 1024) + k0 + lc, (char*)As + (i * 32 + wave * 8) * 128);
    }
#pragma unroll
    for (int i = 0; i < 4; i++) {
      int row = i * 32 + wave * 8 + lr;
      gload16(Bb + (size_t)row * (49 * 1024) + k0 + lc, (char*)Bs + (i * 32 + wave * 8) * 128);
    }
    __syncthreads();
#pragma unroll
    for (int kt = 0; kt < 2; kt++) {
      int ko = (((kt << 2) | (lane >> 4)) ^ key) << 3;
      short8 af[4], bfr[2];
#pragma unroll
      for (int i = 0; i < 4; i++)
        af[i] = *(const short8*)(As + (i * 16 + (lane & 15)) * 64 + ko);
#pragma unroll
      for (int j = 0; j < 2; j++)
        bfr[j] = *(const short8*)(Bs + (wave * 32 + j * 16 + (lane & 15)) * 64 + ko);
#pragma unroll
      for (int i = 0; i < 4; i++)
#pragma unroll
        for (int j = 0; j < 2; j++)
          acc[i][j] = __builtin_amdgcn_mfma_f32_16x16x32_bf16(af[i], bfr[j], acc[i][j], 0, 0, 0);
    }
    __syncthreads();
  }
  // store partials P[ij][nroi][112] bf16 (c>=112 dropped; only c<105 used)
  unsigned short* Pb = P + (size_t)ij * nroi * 112;
#pragma unroll
  for (int i = 0; i < 4; i++)
#pragma unroll
    for (int j = 0; j < 2; j++) {
      int cc = wave * 32 + j * 16 + (lane & 15);
      if (cc < 112) {
        int rbase = mt * 64 + i * 16 + (lane >> 4) * 4;
#pragma unroll
        for (int r = 0; r < 4; r++)
          Pb[(size_t)(rbase + r) * 112 + cc] = f2bf(acc[i][j][r]);
      }
    }
}

// --- reduce 49 ij-partials -> score ----------------------------------------
__global__ __launch_bounds__(256) void k_reduce(const unsigned short* __restrict__ P,
                                                float* __restrict__ score, int nroi) {
  int t = blockIdx.x * 256 + threadIdx.x;   // nroi*112
  if (t >= nroi * 112) return;
  int roi = t / 112, c = t - roi * 112;
  float s = 0.f;
#pragma unroll 7
  for (int ij = 0; ij < 49; ij++) s += bf2f(P[(size_t)ij * nroi * 112 + t]);
  score[(size_t)roi * 128 + c] = s;
}

// --- epilogue: softmax(cls/49) + bbox/49 -----------------------------------
__global__ __launch_bounds__(256) void k_final(const float* __restrict__ score,
                                               float* __restrict__ out) {
  int t = blockIdx.x * 256 + threadIdx.x;
  if (t < 1200) {
    float s[21];
    float mx = -1e30f;
#pragma unroll
    for (int c = 0; c < 21; c++) {
      s[c] = score[(size_t)t * 128 + c] * (1.f / 49.f);
      mx = fmaxf(mx, s[c]);
    }
    float sum = 0.f;
#pragma unroll
    for (int c = 0; c < 21; c++) { s[c] = expf(s[c] - mx); sum += s[c]; }
    float rs = 1.f / sum;
#pragma unroll
    for (int c = 0; c < 21; c++) out[(size_t)t * 21 + c] = s[c] * rs;
  }
  if (t < 100800) {
    int roi = t / 84, c = t - (t / 84) * 84;
    out[25200 + t] = score[(size_t)roi * 128 + 21 + c] * (1.f / 49.f);
  }
}

extern "C" void kernel_launch(void* const* d_in, const int* in_sizes, int n_in,
                              void* d_out, int out_size, void* d_ws, size_t ws_size,
                              hipStream_t stream) {
  const float* base_feat = (const float*)d_in[0];
  const float* rois      = (const float*)d_in[1];
  const float* w_conv1   = (const float*)d_in[2];
  const float* w_cls     = (const float*)d_in[3];
  const float* w_bbox    = (const float*)d_in[4];
  float* out = (float*)d_out;
  char* ws = (char*)d_ws;

  unsigned short* featT = (unsigned short*)(ws + OFF_FEATT);
  unsigned short* w1b   = (unsigned short*)(ws + OFF_W1);
  unsigned short* Wc    = (unsigned short*)(ws + OFF_WC);
  int*            desc  = (int*)(ws + OFF_DESC);
  float*          score = (float*)(ws + OFF_SCORE);
  float*          X     = (float*)(ws + OFF_X);

  k_cvt_w1<<<2048, 256, 0, stream>>>(w_conv1, w1b);
  k_cvt_wcomb<<<6272, 256, 0, stream>>>(w_cls, w_bbox, Wc);
  k_tpose<<<dim3(64, 32, 4), 256, 0, stream>>>(base_feat, featT);
  k_gemm_conv1<<<dim3(32, 8, 4), 256, 0, stream>>>((const short*)featT, (const short*)w1b, X);
  k_desc<<<245, 256, 0, stream>>>(rois, desc);

  if (ws_size >= ONEPASS_BYTES) {
    unsigned short* U = (unsigned short*)(ws + OFF_U1);
    unsigned short* P = (unsigned short*)(ws + OFF_P1);
    k_ubuild<<<1280 * 49, 256, 0, stream>>>(X, desc, U);
    k_poolgemm2<<<dim3(20, 49), 256, 0, stream>>>(U, Wc, P, 1280);
    k_reduce<<<560, 256, 0, stream>>>(P, score, 1280);
  } else {
    unsigned short* U = (unsigned short*)(ws + OFF_U2);
    unsigned short* P = (unsigned short*)(ws + OFF_P2);
    for (int h = 0; h < 2; h++) {
      k_ubuild<<<640 * 49, 256, 0, stream>>>(X, desc + (size_t)h * 640 * 49 * 8, U);
      k_poolgemm2<<<dim3(10, 49), 256, 0, stream>>>(U, Wc, P, 640);
      k_reduce<<<280, 256, 0, stream>>>(P, score + (size_t)h * 640 * 128, 640);
    }
  }
  k_final<<<394, 256, 0, stream>>>(score, out);
}